// Round 2
// baseline (329.993 us; speedup 1.0000x reference)
//
#include <hip/hip_runtime.h>
#include <hip/hip_bf16.h>
#include <math.h>

#define B_ 4
#define N_ 4096
#define M_ 1024
#define C_ 384
#define NH_ 8
#define HD_ 48

typedef float f32x4 __attribute__((ext_vector_type(4)));
typedef short bf16x8 __attribute__((ext_vector_type(8)));

typedef __attribute__((address_space(3))) unsigned int lds_uint;
typedef const __attribute__((address_space(1))) unsigned int glob_uint;

__device__ __forceinline__ void gld_lds16(const void* g, void* l) {
    // async global->LDS, 16 B/lane; LDS dest = wave-uniform base + lane*16
    __builtin_amdgcn_global_load_lds((glob_uint*)g, (lds_uint*)l, 16, 0, 0);
}

__device__ __forceinline__ unsigned short f2bf(float x) {  // RNE
    unsigned int u = __builtin_bit_cast(unsigned int, x);
    return (unsigned short)((u + 0x7FFFu + ((u >> 16) & 1u)) >> 16);
}
__device__ __forceinline__ unsigned short f2bf_trunc(float x) {
    return (unsigned short)(__builtin_bit_cast(unsigned int, x) >> 16);
}
__device__ __forceinline__ float bf2f(unsigned short x) {
    return __builtin_bit_cast(float, (unsigned int)x << 16);
}
__device__ __forceinline__ float fast_exp2(float x) {
#if __has_builtin(__builtin_amdgcn_exp2f)
    return __builtin_amdgcn_exp2f(x);
#else
    return exp2f(x);
#endif
}
__device__ __forceinline__ uint2 pack4_rne(float a, float b, float c, float d) {
    uint2 r;
    r.x = (unsigned int)f2bf(a) | ((unsigned int)f2bf(b) << 16);
    r.y = (unsigned int)f2bf(c) | ((unsigned int)f2bf(d) << 16);
    return r;
}

// 48^-0.5 * log2(e): softmax via 2^x
#define QSCALE 0.20823490983597203f

// ---------------------------------------------------------------------------
// Fused prep: blocks [0,7680) convert activations fp32->bf16 (flat float4
// grid; q_x then kv_x); blocks [7680,7824) transpose+convert weights.
// ---------------------------------------------------------------------------
__global__ __launch_bounds__(256)
void prep(const float* __restrict__ qx_f, unsigned short* __restrict__ qx_bf,
          const float* __restrict__ kvx_f, unsigned short* __restrict__ kvx_bf,
          const float* __restrict__ Wq, const float* __restrict__ Wkv,
          const float* __restrict__ Wproj,
          unsigned short* __restrict__ Wq_t, unsigned short* __restrict__ Wkv_t,
          unsigned short* __restrict__ Wproj_t)
{
    __shared__ unsigned short T[64 * 72];
    const int tid = threadIdx.x;
    int bid = blockIdx.x;

    if (bid < 7680) {
        size_t i4 = (size_t)bid * 256 + tid;
        const float* src; unsigned short* dst;
        if (i4 < 1572864u) { src = qx_f; dst = qx_bf; }
        else { src = kvx_f; dst = kvx_bf; i4 -= 1572864u; }
        float4 v = *(const float4*)&src[i4 * 4];
        *(uint2*)&dst[i4 * 4] = pack4_rne(v.x, v.y, v.z, v.w);
        return;
    }

    bid -= 7680;
    const float* W; unsigned short* Wt; int N, kt, nt;
    if (bid < 36)       { W = Wq;    Wt = Wq_t;    N = 384; kt = bid / 6;  nt = bid - kt * 6; }
    else if (bid < 108) { bid -= 36;  W = Wkv;   Wt = Wkv_t;   N = 768; kt = bid / 12; nt = bid - kt * 12; }
    else                { bid -= 108; W = Wproj; Wt = Wproj_t; N = 384; kt = bid / 6;  nt = bid - kt * 6; }
    const int k0 = kt * 64, n0 = nt * 64;

    #pragma unroll
    for (int it = 0; it < 4; ++it) {
        int k = it * 16 + (tid >> 4);
        int n4 = (tid & 15) * 4;
        float4 v = *(const float4*)&W[(size_t)(k0 + k) * N + n0 + n4];
        T[(n4 + 0) * 72 + k] = f2bf(v.x);
        T[(n4 + 1) * 72 + k] = f2bf(v.y);
        T[(n4 + 2) * 72 + k] = f2bf(v.z);
        T[(n4 + 3) * 72 + k] = f2bf(v.w);
    }
    __syncthreads();
    #pragma unroll
    for (int i = 0; i < 2; ++i) {
        int s = tid + 256 * i;
        int n = s >> 3, part = s & 7;
        *(uint4*)&Wt[(size_t)(n0 + n) * C_ + k0 + part * 8] = *(const uint4*)&T[n * 72 + part * 8];
    }
}

// ---------------------------------------------------------------------------
// m97-style GEMM core: 128x128 tile, BK=64, global_load_lds staging with
// XOR-8 chunk swizzle (conflict-free ds_read_b128, no padding needed).
// Both operands are bf16 [row][384]. Operand-swapped MFMA: thread owns
// row = rowbase+rt*16+ln, cols = colbase+ct*16+quad*4+{0..3}.
// ---------------------------------------------------------------------------
// stage 128 rows x 64 cols from src (row stride 384 bf16) into 16 KB LDS.
// LDS slot (row, c) holds global chunk c ^ (row & 7).  (chunk = 16 B)
__device__ __forceinline__ void stage128(const unsigned short* src, unsigned short* lds,
                                         int kk, int tid) {
    #pragma unroll
    for (int r = 0; r < 4; ++r) {
        int off = r * 256 + tid;          // 16B-slot index 0..1023
        int row = off >> 3;
        int c = off & 7;
        int gc = c ^ (row & 7);
        gld_lds16(src + (size_t)row * C_ + kk + gc * 8, lds + (size_t)off * 8);
    }
}
__device__ __forceinline__ bf16x8 frag_ld(const unsigned short* lds, int row, int chunk) {
    return *(const bf16x8*)&lds[row * 64 + ((chunk ^ (row & 7)) << 3)];
}

#define GEMM_CORE(Aptr, Wptr)                                                        \
    f32x4 acc[4][4];                                                                 \
    _Pragma("unroll")                                                                \
    for (int rt = 0; rt < 4; ++rt)                                                   \
        _Pragma("unroll")                                                            \
        for (int ct = 0; ct < 4; ++ct) acc[rt][ct] = (f32x4){0.f, 0.f, 0.f, 0.f};    \
    const int wrow0 = (wave & 1) * 64;                                               \
    const int wcol0 = (wave >> 1) * 64;                                              \
    for (int kk = 0; kk < C_; kk += 64) {                                            \
        __syncthreads();                                                             \
        stage128(Aptr, As, kk, tid);                                                 \
        stage128(Wptr, Ws, kk, tid);                                                 \
        __syncthreads();                                                             \
        _Pragma("unroll")                                                            \
        for (int ks = 0; ks < 2; ++ks) {                                             \
            bf16x8 af[4], wf[4];                                                     \
            _Pragma("unroll")                                                        \
            for (int rt = 0; rt < 4; ++rt)                                           \
                af[rt] = frag_ld(As, wrow0 + rt * 16 + ln, ks * 4 + quad);           \
            _Pragma("unroll")                                                        \
            for (int ct = 0; ct < 4; ++ct)                                           \
                wf[ct] = frag_ld(Ws, wcol0 + ct * 16 + ln, ks * 4 + quad);           \
            _Pragma("unroll")                                                        \
            for (int rt = 0; rt < 4; ++rt)                                           \
                _Pragma("unroll")                                                    \
                for (int ct = 0; ct < 4; ++ct)                                       \
                    acc[rt][ct] = __builtin_amdgcn_mfma_f32_16x16x32_bf16(           \
                        wf[ct], af[rt], acc[rt][ct], 0, 0, 0);                       \
        }                                                                            \
    }

// ---------------------------------------------------------------------------
// Fused q-proj (blocks [0,384)) + kv-proj (blocks [384,576)).
// ---------------------------------------------------------------------------
__global__ __launch_bounds__(256)
void gemm_qkv(const unsigned short* __restrict__ qx, const unsigned short* __restrict__ kvx,
              const unsigned short* __restrict__ Wqt, const unsigned short* __restrict__ Wkvt,
              unsigned short* __restrict__ qbf, unsigned short* __restrict__ qres,
              unsigned short* __restrict__ kbf, unsigned short* __restrict__ vbf)
{
    __shared__ unsigned short As[128 * 64];
    __shared__ unsigned short Ws[128 * 64];
    const int tid = threadIdx.x;
    const int wave = tid >> 6;
    const int lane = tid & 63;
    const int ln = lane & 15;
    const int quad = lane >> 4;

    int bid = blockIdx.x;
    int mode, row0, col0;
    const unsigned short *A, *Wt;
    if (bid < 384) { mode = 0; A = qx;  Wt = Wqt;  row0 = (bid / 3) * 128; col0 = (bid % 3) * 128; }
    else { bid -= 384; mode = 1; A = kvx; Wt = Wkvt; row0 = (bid / 6) * 128; col0 = (bid % 6) * 128; }

    GEMM_CORE(A + (size_t)row0 * C_, Wt + (size_t)col0 * C_)

    #pragma unroll
    for (int rt = 0; rt < 4; ++rt) {
        int grow = row0 + wrow0 + rt * 16 + ln;
        #pragma unroll
        for (int ct = 0; ct < 4; ++ct) {
            int col = col0 + wcol0 + ct * 16 + quad * 4;
            f32x4 v = acc[rt][ct];
            if (mode == 0) {
                *(uint2*)&qres[(size_t)grow * C_ + col] = pack4_rne(v[0], v[1], v[2], v[3]);
                int b = grow >> 12, n = grow & (N_ - 1);
                int h = col / HD_, d = col - h * HD_;
                *(uint2*)&qbf[(((size_t)(b * NH_ + h) * N_) + n) * HD_ + d] =
                    pack4_rne(v[0] * QSCALE, v[1] * QSCALE, v[2] * QSCALE, v[3] * QSCALE);
            } else {
                int b = grow >> 10, m = grow & (M_ - 1);
                if (col < C_) {
                    int h = col / HD_, d = col - h * HD_;
                    *(uint2*)&kbf[(((size_t)(b * NH_ + h) * M_) + m) * HD_ + d] =
                        pack4_rne(v[0], v[1], v[2], v[3]);
                } else {
                    int c2 = col - C_;
                    int h = c2 / HD_, d = c2 - h * HD_;
                    size_t base = ((size_t)(b * NH_ + h) * HD_ + d) * M_ + m;
                    #pragma unroll
                    for (int r = 0; r < 4; ++r) vbf[base + (size_t)r * M_] = f2bf(v[r]);
                }
            }
        }
    }
}

// ---------------------------------------------------------------------------
// Out-proj: out = qres + of @ Wproj + bias. 384 blocks.
// ---------------------------------------------------------------------------
__global__ __launch_bounds__(256)
void gemm_out(const unsigned short* __restrict__ A, const unsigned short* __restrict__ Wt,
              float* __restrict__ out0,
              const unsigned short* __restrict__ addend, const float* __restrict__ bias)
{
    __shared__ unsigned short As[128 * 64];
    __shared__ unsigned short Ws[128 * 64];
    const int tid = threadIdx.x;
    const int wave = tid >> 6;
    const int lane = tid & 63;
    const int ln = lane & 15;
    const int quad = lane >> 4;
    const int row0 = (blockIdx.x / 3) * 128;
    const int col0 = (blockIdx.x % 3) * 128;

    GEMM_CORE(A + (size_t)row0 * C_, Wt + (size_t)col0 * C_)

    #pragma unroll
    for (int rt = 0; rt < 4; ++rt) {
        int grow = row0 + wrow0 + rt * 16 + ln;
        #pragma unroll
        for (int ct = 0; ct < 4; ++ct) {
            int col = col0 + wcol0 + ct * 16 + quad * 4;
            f32x4 v = acc[rt][ct];
            size_t idx = (size_t)grow * C_ + col;
            uint2 ad = *(const uint2*)&addend[idx];
            float4 bi = *(const float4*)&bias[col];
            float4 o;
            o.x = v[0] + bf2f((unsigned short)(ad.x & 0xFFFF)) + bi.x;
            o.y = v[1] + bf2f((unsigned short)(ad.x >> 16))    + bi.y;
            o.z = v[2] + bf2f((unsigned short)(ad.y & 0xFFFF)) + bi.z;
            o.w = v[3] + bf2f((unsigned short)(ad.y >> 16))    + bi.w;
            *(float4*)&out0[idx] = o;
        }
    }
}

// ---------------------------------------------------------------------------
// MFMA attention, R8: 8 waves / 512 threads per block. Waves are paired on
// the M (KV) axis: waves 0-3 own q-chunks 0-3 with mt in [0,8); waves 4-7
// own the SAME q-chunks with mt in [8,16). Per-wave MFMA:load amortization
// equals the R6 64-q-row version, but waves/CU doubles (8 -> 16; grid 512
// blocks x 8 waves, 2 blocks/CU). exp2-no-max softmax means partials merge
// by pure addition: upper waves export O + rs through the (finished) P LDS
// region, lower waves add, normalize, store.
// ---------------------------------------------------------------------------
__global__ __launch_bounds__(512, 4)
void attn_mfma(const unsigned short* __restrict__ qbf,
               const unsigned short* __restrict__ kbf,
               const unsigned short* __restrict__ vbf,
               unsigned short* __restrict__ of)
{
    __shared__ unsigned short P[8][64 * 72];   // per-wave [q][m]

    const int tid = threadIdx.x;
    const int wave = tid >> 6;
    const int qwave = wave & 3;     // q-chunk owner
    const int mhalf = wave >> 2;    // 0: mt 0..7, 1: mt 8..15
    const int lane = tid & 63;
    const int ln = lane & 15;
    const int quad = lane >> 4;
    const int bh = blockIdx.x;
    const int n0w = blockIdx.y * 256 + qwave * 64;

    const bf16x8 zero8 = (bf16x8){0, 0, 0, 0, 0, 0, 0, 0};

    bf16x8 qb[4][2];
    #pragma unroll
    for (int qt = 0; qt < 4; ++qt) {
        const unsigned short* qp = qbf + ((size_t)bh * N_ + n0w + qt * 16 + ln) * HD_;
        qb[qt][0] = *(const bf16x8*)(qp + quad * 8);
        qb[qt][1] = *(const bf16x8*)(qp + 32 + quad * 8);   // overread ok
        if (quad >= 2) qb[qt][1] = zero8;
    }

    f32x4 O[3][4];
    #pragma unroll
    for (int ot = 0; ot < 3; ++ot)
        #pragma unroll
        for (int qt = 0; qt < 4; ++qt) O[ot][qt] = (f32x4){0.f, 0.f, 0.f, 0.f};
    float rs[4] = {0.f, 0.f, 0.f, 0.f};

    const unsigned short* kb = kbf + (size_t)bh * M_ * HD_;
    const unsigned short* vb = vbf + (size_t)bh * HD_ * M_;
    unsigned short* Pw = &P[wave][0];

    const int mt0 = mhalf * 8;
    for (int mt = mt0; mt < mt0 + 8; ++mt) {
        bf16x8 va[3][2];
        #pragma unroll
        for (int ot = 0; ot < 3; ++ot) {
            const unsigned short* vp = vb + (size_t)(ot * 16 + ln) * M_ + mt * 64;
            va[ot][0] = *(const bf16x8*)(vp + quad * 8);
            va[ot][1] = *(const bf16x8*)(vp + 32 + quad * 8);
        }
        bf16x8 ka[4][2];
        #pragma unroll
        for (int t = 0; t < 4; ++t) {
            const unsigned short* kp = kb + (size_t)(mt * 64 + t * 16 + ln) * HD_;
            ka[t][0] = *(const bf16x8*)(kp + quad * 8);
            ka[t][1] = *(const bf16x8*)(kp + 32 + quad * 8);
            if (quad >= 2) ka[t][1] = zero8;
        }

        #pragma unroll
        for (int t = 0; t < 4; ++t) {
            #pragma unroll
            for (int qt = 0; qt < 4; ++qt) {
                f32x4 s = (f32x4){0.f, 0.f, 0.f, 0.f};
                s = __builtin_amdgcn_mfma_f32_16x16x32_bf16(ka[t][0], qb[qt][0], s, 0, 0, 0);
                s = __builtin_amdgcn_mfma_f32_16x16x32_bf16(ka[t][1], qb[qt][1], s, 0, 0, 0);
                float p0 = fast_exp2(s[0]);
                float p1 = fast_exp2(s[1]);
                float p2 = fast_exp2(s[2]);
                float p3 = fast_exp2(s[3]);
                rs[qt] += (p0 + p1) + (p2 + p3);
                uint2 pk;
                pk.x = (unsigned int)f2bf_trunc(p0) | ((unsigned int)f2bf_trunc(p1) << 16);
                pk.y = (unsigned int)f2bf_trunc(p2) | ((unsigned int)f2bf_trunc(p3) << 16);
                *(uint2*)&Pw[(qt * 16 + ln) * 72 + t * 16 + quad * 4] = pk;
            }
        }

        #pragma unroll
        for (int qt = 0; qt < 4; ++qt) {
            const unsigned short* Pr = &Pw[(qt * 16 + ln) * 72];
            bf16x8 pb0 = *(const bf16x8*)(Pr + quad * 8);
            bf16x8 pb1 = *(const bf16x8*)(Pr + 32 + quad * 8);
            #pragma unroll
            for (int ot = 0; ot < 3; ++ot) {
                O[ot][qt] = __builtin_amdgcn_mfma_f32_16x16x32_bf16(va[ot][0], pb0, O[ot][qt], 0, 0, 0);
                O[ot][qt] = __builtin_amdgcn_mfma_f32_16x16x32_bf16(va[ot][1], pb1, O[ot][qt], 0, 0, 0);
            }
        }
    }

    // ---- pair-combine over the M split (exp2-no-max: pure addition) ----
    // Upper waves (mhalf=1) export O (48 f32) + rs (4 f32) per lane into the
    // finished P region; lower waves add. 4 waves x 64 lanes x 52 f32 = 52 KB.
    __syncthreads();                       // everyone done reading their P
    float* exb = (float*)&P[0][0];
    if (mhalf) {
        float* ex = exb + ((size_t)qwave * 64 + lane) * 52;
        #pragma unroll
        for (int ot = 0; ot < 3; ++ot)
            #pragma unroll
            for (int qt = 0; qt < 4; ++qt)
                *(f32x4*)&ex[(ot * 4 + qt) * 4] = O[ot][qt];
        #pragma unroll
        for (int qt = 0; qt < 4; ++qt) ex[48 + qt] = rs[qt];
    }
    __syncthreads();
    if (mhalf) return;

    {
        const float* ex = exb + ((size_t)qwave * 64 + lane) * 52;
        #pragma unroll
        for (int ot = 0; ot < 3; ++ot)
            #pragma unroll
            for (int qt = 0; qt < 4; ++qt) {
                f32x4 u = *(const f32x4*)&ex[(ot * 4 + qt) * 4];
                O[ot][qt] += u;
            }
        #pragma unroll
        for (int qt = 0; qt < 4; ++qt) rs[qt] += ex[48 + qt];
    }

    float inv[4];
    #pragma unroll
    for (int qt = 0; qt < 4; ++qt) {
        float x = rs[qt];
        x += __shfl_xor(x, 16);
        x += __shfl_xor(x, 32);
        inv[qt] = 1.0f / x;
    }

    const int b = bh >> 3, h = bh & 7;
    #pragma unroll
    for (int ot = 0; ot < 3; ++ot)
        #pragma unroll
        for (int qt = 0; qt < 4; ++qt) {
            size_t grow = (size_t)b * N_ + n0w + qt * 16 + ln;
            int gcol = h * HD_ + ot * 16 + quad * 4;
            *(uint2*)&of[grow * C_ + gcol] =
                pack4_rne(O[ot][qt][0] * inv[qt], O[ot][qt][1] * inv[qt],
                          O[ot][qt][2] * inv[qt], O[ot][qt][3] * inv[qt]);
        }
}

extern "C" void kernel_launch(void* const* d_in, const int* in_sizes, int n_in,
                              void* d_out, int out_size, void* d_ws, size_t ws_size,
                              hipStream_t stream) {
    const float* q_x   = (const float*)d_in[0];
    const float* kv_x  = (const float*)d_in[1];
    const float* Wq    = (const float*)d_in[2];
    const float* Wkv   = (const float*)d_in[3];
    const float* Wproj = (const float*)d_in[4];
    const float* bproj = (const float*)d_in[5];
    float* out = (float*)d_out;

    unsigned short* qbf     = (unsigned short*)d_ws;  // [B,H,N,48] scaled
    unsigned short* kbf     = qbf     + 6291456;      // [B,H,M,48]
    unsigned short* vbf     = kbf     + 1572864;      // [B,H,48,M]
    unsigned short* qres    = vbf     + 1572864;      // [B,N,384] bf16 residual
    unsigned short* of      = qres    + 6291456;      // [B,N,384] bf16 attn out
    unsigned short* qx_bf   = of      + 6291456;      // [B,N,384] bf16
    unsigned short* kvx_bf  = qx_bf   + 6291456;      // [B,M,384] bf16
    unsigned short* Wq_t    = kvx_bf  + 1572864;      // [384][384]
    unsigned short* Wkv_t   = Wq_t    + 147456;       // [768][384]
    unsigned short* Wproj_t = Wkv_t   + 294912;       // [384][384]

    dim3 blk(256);

    // fused activation convert + weight transpose
    prep<<<dim3(7824), blk, 0, stream>>>(q_x, qx_bf, kv_x, kvx_bf,
                                         Wq, Wkv, Wproj, Wq_t, Wkv_t, Wproj_t);

    // fused q-proj + kv-proj (m97-style, global_load_lds staging)
    gemm_qkv<<<dim3(576), blk, 0, stream>>>(
        qx_bf, kvx_bf, Wq_t, Wkv_t, qbf, qres, kbf, vbf);

    // attention: 512 blocks x 8 waves (M-split pairs), 2 blocks/CU
    attn_mfma<<<dim3(32, 16), dim3(512), 0, stream>>>(qbf, kbf, vbf, of);

    // out = qres + of @ Wproj + bproj
    gemm_out<<<dim3(384), blk, 0, stream>>>(of, Wproj_t, out, qres, bproj);
}

// Round 3
// 169.700 us; speedup vs baseline: 1.9446x; 1.9446x over previous
//
#include <hip/hip_runtime.h>
#include <hip/hip_bf16.h>
#include <math.h>

#define B_ 4
#define N_ 4096
#define M_ 1024
#define C_ 384
#define NH_ 8
#define HD_ 48

typedef float f32x4 __attribute__((ext_vector_type(4)));
typedef short bf16x8 __attribute__((ext_vector_type(8)));

typedef __attribute__((address_space(3))) unsigned int lds_uint;
typedef const __attribute__((address_space(1))) unsigned int glob_uint;

__device__ __forceinline__ void gld_lds16(const void* g, void* l) {
    // async global->LDS, 16 B/lane; LDS dest = wave-uniform base + lane*16
    __builtin_amdgcn_global_load_lds((glob_uint*)g, (lds_uint*)l, 16, 0, 0);
}

__device__ __forceinline__ unsigned short f2bf(float x) {  // RNE
    unsigned int u = __builtin_bit_cast(unsigned int, x);
    return (unsigned short)((u + 0x7FFFu + ((u >> 16) & 1u)) >> 16);
}
__device__ __forceinline__ unsigned short f2bf_trunc(float x) {
    return (unsigned short)(__builtin_bit_cast(unsigned int, x) >> 16);
}
__device__ __forceinline__ float bf2f(unsigned short x) {
    return __builtin_bit_cast(float, (unsigned int)x << 16);
}
__device__ __forceinline__ float fast_exp2(float x) {
#if __has_builtin(__builtin_amdgcn_exp2f)
    return __builtin_amdgcn_exp2f(x);
#else
    return exp2f(x);
#endif
}
__device__ __forceinline__ uint2 pack4_rne(float a, float b, float c, float d) {
    uint2 r;
    r.x = (unsigned int)f2bf(a) | ((unsigned int)f2bf(b) << 16);
    r.y = (unsigned int)f2bf(c) | ((unsigned int)f2bf(d) << 16);
    return r;
}

// 48^-0.5 * log2(e): softmax via 2^x
#define QSCALE 0.20823490983597203f

// ---------------------------------------------------------------------------
// Fused prep: blocks [0,7680) convert activations fp32->bf16 (flat float4
// grid; q_x then kv_x); blocks [7680,7824) transpose+convert weights.
// ---------------------------------------------------------------------------
__global__ __launch_bounds__(256)
void prep(const float* __restrict__ qx_f, unsigned short* __restrict__ qx_bf,
          const float* __restrict__ kvx_f, unsigned short* __restrict__ kvx_bf,
          const float* __restrict__ Wq, const float* __restrict__ Wkv,
          const float* __restrict__ Wproj,
          unsigned short* __restrict__ Wq_t, unsigned short* __restrict__ Wkv_t,
          unsigned short* __restrict__ Wproj_t)
{
    __shared__ unsigned short T[64 * 72];
    const int tid = threadIdx.x;
    int bid = blockIdx.x;

    if (bid < 7680) {
        size_t i4 = (size_t)bid * 256 + tid;
        const float* src; unsigned short* dst;
        if (i4 < 1572864u) { src = qx_f; dst = qx_bf; }
        else { src = kvx_f; dst = kvx_bf; i4 -= 1572864u; }
        float4 v = *(const float4*)&src[i4 * 4];
        *(uint2*)&dst[i4 * 4] = pack4_rne(v.x, v.y, v.z, v.w);
        return;
    }

    bid -= 7680;
    const float* W; unsigned short* Wt; int N, kt, nt;
    if (bid < 36)       { W = Wq;    Wt = Wq_t;    N = 384; kt = bid / 6;  nt = bid - kt * 6; }
    else if (bid < 108) { bid -= 36;  W = Wkv;   Wt = Wkv_t;   N = 768; kt = bid / 12; nt = bid - kt * 12; }
    else                { bid -= 108; W = Wproj; Wt = Wproj_t; N = 384; kt = bid / 6;  nt = bid - kt * 6; }
    const int k0 = kt * 64, n0 = nt * 64;

    #pragma unroll
    for (int it = 0; it < 4; ++it) {
        int k = it * 16 + (tid >> 4);
        int n4 = (tid & 15) * 4;
        float4 v = *(const float4*)&W[(size_t)(k0 + k) * N + n0 + n4];
        T[(n4 + 0) * 72 + k] = f2bf(v.x);
        T[(n4 + 1) * 72 + k] = f2bf(v.y);
        T[(n4 + 2) * 72 + k] = f2bf(v.z);
        T[(n4 + 3) * 72 + k] = f2bf(v.w);
    }
    __syncthreads();
    #pragma unroll
    for (int i = 0; i < 2; ++i) {
        int s = tid + 256 * i;
        int n = s >> 3, part = s & 7;
        *(uint4*)&Wt[(size_t)(n0 + n) * C_ + k0 + part * 8] = *(const uint4*)&T[n * 72 + part * 8];
    }
}

// ---------------------------------------------------------------------------
// m97-style GEMM core: 128x128 tile, BK=64, global_load_lds staging with
// XOR-8 chunk swizzle (conflict-free ds_read_b128, no padding needed).
// Both operands are bf16 [row][384]. Operand-swapped MFMA: thread owns
// row = rowbase+rt*16+ln, cols = colbase+ct*16+quad*4+{0..3}.
// ---------------------------------------------------------------------------
// stage 128 rows x 64 cols from src (row stride 384 bf16) into 16 KB LDS.
// LDS slot (row, c) holds global chunk c ^ (row & 7).  (chunk = 16 B)
__device__ __forceinline__ void stage128(const unsigned short* src, unsigned short* lds,
                                         int kk, int tid) {
    #pragma unroll
    for (int r = 0; r < 4; ++r) {
        int off = r * 256 + tid;          // 16B-slot index 0..1023
        int row = off >> 3;
        int c = off & 7;
        int gc = c ^ (row & 7);
        gld_lds16(src + (size_t)row * C_ + kk + gc * 8, lds + (size_t)off * 8);
    }
}
__device__ __forceinline__ bf16x8 frag_ld(const unsigned short* lds, int row, int chunk) {
    return *(const bf16x8*)&lds[row * 64 + ((chunk ^ (row & 7)) << 3)];
}

#define GEMM_CORE(Aptr, Wptr)                                                        \
    f32x4 acc[4][4];                                                                 \
    _Pragma("unroll")                                                                \
    for (int rt = 0; rt < 4; ++rt)                                                   \
        _Pragma("unroll")                                                            \
        for (int ct = 0; ct < 4; ++ct) acc[rt][ct] = (f32x4){0.f, 0.f, 0.f, 0.f};    \
    const int wrow0 = (wave & 1) * 64;                                               \
    const int wcol0 = (wave >> 1) * 64;                                              \
    for (int kk = 0; kk < C_; kk += 64) {                                            \
        __syncthreads();                                                             \
        stage128(Aptr, As, kk, tid);                                                 \
        stage128(Wptr, Ws, kk, tid);                                                 \
        __syncthreads();                                                             \
        _Pragma("unroll")                                                            \
        for (int ks = 0; ks < 2; ++ks) {                                             \
            bf16x8 af[4], wf[4];                                                     \
            _Pragma("unroll")                                                        \
            for (int rt = 0; rt < 4; ++rt)                                           \
                af[rt] = frag_ld(As, wrow0 + rt * 16 + ln, ks * 4 + quad);           \
            _Pragma("unroll")                                                        \
            for (int ct = 0; ct < 4; ++ct)                                           \
                wf[ct] = frag_ld(Ws, wcol0 + ct * 16 + ln, ks * 4 + quad);           \
            _Pragma("unroll")                                                        \
            for (int rt = 0; rt < 4; ++rt)                                           \
                _Pragma("unroll")                                                    \
                for (int ct = 0; ct < 4; ++ct)                                       \
                    acc[rt][ct] = __builtin_amdgcn_mfma_f32_16x16x32_bf16(           \
                        wf[ct], af[rt], acc[rt][ct], 0, 0, 0);                       \
        }                                                                            \
    }

// ---------------------------------------------------------------------------
// Fused q-proj (blocks [0,384)) + kv-proj (blocks [384,576)).
// ---------------------------------------------------------------------------
__global__ __launch_bounds__(256)
void gemm_qkv(const unsigned short* __restrict__ qx, const unsigned short* __restrict__ kvx,
              const unsigned short* __restrict__ Wqt, const unsigned short* __restrict__ Wkvt,
              unsigned short* __restrict__ qbf, unsigned short* __restrict__ qres,
              unsigned short* __restrict__ kbf, unsigned short* __restrict__ vbf)
{
    __shared__ unsigned short As[128 * 64];
    __shared__ unsigned short Ws[128 * 64];
    const int tid = threadIdx.x;
    const int wave = tid >> 6;
    const int lane = tid & 63;
    const int ln = lane & 15;
    const int quad = lane >> 4;

    int bid = blockIdx.x;
    int mode, row0, col0;
    const unsigned short *A, *Wt;
    if (bid < 384) { mode = 0; A = qx;  Wt = Wqt;  row0 = (bid / 3) * 128; col0 = (bid % 3) * 128; }
    else { bid -= 384; mode = 1; A = kvx; Wt = Wkvt; row0 = (bid / 6) * 128; col0 = (bid % 6) * 128; }

    GEMM_CORE(A + (size_t)row0 * C_, Wt + (size_t)col0 * C_)

    #pragma unroll
    for (int rt = 0; rt < 4; ++rt) {
        int grow = row0 + wrow0 + rt * 16 + ln;
        #pragma unroll
        for (int ct = 0; ct < 4; ++ct) {
            int col = col0 + wcol0 + ct * 16 + quad * 4;
            f32x4 v = acc[rt][ct];
            if (mode == 0) {
                *(uint2*)&qres[(size_t)grow * C_ + col] = pack4_rne(v[0], v[1], v[2], v[3]);
                int b = grow >> 12, n = grow & (N_ - 1);
                int h = col / HD_, d = col - h * HD_;
                *(uint2*)&qbf[(((size_t)(b * NH_ + h) * N_) + n) * HD_ + d] =
                    pack4_rne(v[0] * QSCALE, v[1] * QSCALE, v[2] * QSCALE, v[3] * QSCALE);
            } else {
                int b = grow >> 10, m = grow & (M_ - 1);
                if (col < C_) {
                    int h = col / HD_, d = col - h * HD_;
                    *(uint2*)&kbf[(((size_t)(b * NH_ + h) * M_) + m) * HD_ + d] =
                        pack4_rne(v[0], v[1], v[2], v[3]);
                } else {
                    int c2 = col - C_;
                    int h = c2 / HD_, d = c2 - h * HD_;
                    size_t base = ((size_t)(b * NH_ + h) * HD_ + d) * M_ + m;
                    #pragma unroll
                    for (int r = 0; r < 4; ++r) vbf[base + (size_t)r * M_] = f2bf(v[r]);
                }
            }
        }
    }
}

// ---------------------------------------------------------------------------
// Out-proj: out = qres + of @ Wproj + bias. 384 blocks.
// ---------------------------------------------------------------------------
__global__ __launch_bounds__(256)
void gemm_out(const unsigned short* __restrict__ A, const unsigned short* __restrict__ Wt,
              float* __restrict__ out0,
              const unsigned short* __restrict__ addend, const float* __restrict__ bias)
{
    __shared__ unsigned short As[128 * 64];
    __shared__ unsigned short Ws[128 * 64];
    const int tid = threadIdx.x;
    const int wave = tid >> 6;
    const int lane = tid & 63;
    const int ln = lane & 15;
    const int quad = lane >> 4;
    const int row0 = (blockIdx.x / 3) * 128;
    const int col0 = (blockIdx.x % 3) * 128;

    GEMM_CORE(A + (size_t)row0 * C_, Wt + (size_t)col0 * C_)

    #pragma unroll
    for (int rt = 0; rt < 4; ++rt) {
        int grow = row0 + wrow0 + rt * 16 + ln;
        #pragma unroll
        for (int ct = 0; ct < 4; ++ct) {
            int col = col0 + wcol0 + ct * 16 + quad * 4;
            f32x4 v = acc[rt][ct];
            size_t idx = (size_t)grow * C_ + col;
            uint2 ad = *(const uint2*)&addend[idx];
            float4 bi = *(const float4*)&bias[col];
            float4 o;
            o.x = v[0] + bf2f((unsigned short)(ad.x & 0xFFFF)) + bi.x;
            o.y = v[1] + bf2f((unsigned short)(ad.x >> 16))    + bi.y;
            o.z = v[2] + bf2f((unsigned short)(ad.y & 0xFFFF)) + bi.z;
            o.w = v[3] + bf2f((unsigned short)(ad.y >> 16))    + bi.w;
            *(float4*)&out0[idx] = o;
        }
    }
}

// ---------------------------------------------------------------------------
// MFMA attention R9: R0 structure (4 waves x 64 q-rows, grid (32,16),
// 2 blocks/CU) + block-shared double-buffered LDS K/V staging via
// global_load_lds (T3 minimum 2-phase: stage next tile, compute current,
// one vmcnt(0)+s_barrier per tile). K/V tiles [64][64] with XOR-8 chunk
// swizzle (GEMM-proven conflict-free ds_read_b128); K rows (48 cols) padded
// to 8 chunks by harmless overread so staging is unmasked and per-wave
// vmcnt counts stay uniform. Raw s_barrier (no __syncthreads full-drain).
// ---------------------------------------------------------------------------
__global__ __launch_bounds__(256, 2)
void attn_mfma(const unsigned short* __restrict__ qbf,
               const unsigned short* __restrict__ kbf,
               const unsigned short* __restrict__ vbf,
               unsigned short* __restrict__ of)
{
    __shared__ unsigned short Ks[2][64 * 64];   // [m 0..63][hd chunks, XOR-8]
    __shared__ unsigned short Vs[2][64 * 64];   // [d 0..63(48 valid)][m chunks, XOR-8]
    __shared__ unsigned short P[4][64 * 72];    // per-wave [q][m]

    const int tid = threadIdx.x;
    const int wave = tid >> 6;
    const int lane = tid & 63;
    const int ln = lane & 15;
    const int quad = lane >> 4;
    const int bh = blockIdx.x;
    const int n0w = blockIdx.y * 256 + wave * 64;

    const bf16x8 zero8 = (bf16x8){0, 0, 0, 0, 0, 0, 0, 0};

    const unsigned short* kb = kbf + (size_t)bh * M_ * HD_;
    const unsigned short* vb = vbf + (size_t)bh * HD_ * M_;
    unsigned short* Pw = &P[wave][0];

    // Q fragments (held in registers for the whole kernel)
    bf16x8 qb[4][2];
    #pragma unroll
    for (int qt = 0; qt < 4; ++qt) {
        const unsigned short* qp = qbf + ((size_t)bh * N_ + n0w + qt * 16 + ln) * HD_;
        qb[qt][0] = *(const bf16x8*)(qp + quad * 8);
        qb[qt][1] = *(const bf16x8*)(qp + 32 + quad * 8);   // overread ok
        if (quad >= 2) qb[qt][1] = zero8;
    }

    f32x4 O[3][4];
    #pragma unroll
    for (int ot = 0; ot < 3; ++ot)
        #pragma unroll
        for (int qt = 0; qt < 4; ++qt) O[ot][qt] = (f32x4){0.f, 0.f, 0.f, 0.f};
    float rs[4] = {0.f, 0.f, 0.f, 0.f};

    // stage one 64-m tile of K and V into LDS buffer `buf`.
    // slot s in [0,512): row = s>>3, chunk c = s&7, global chunk gc = c^(row&7).
    // K: row-stride 48 shorts; gc=6,7 overread into next row (never read back).
    // V: rows 48..63 overread past this bh's V (never read back).
#define STAGE_KV(buf, mt)                                                     \
    {                                                                         \
        const int m0s = (mt) * 64;                                            \
        _Pragma("unroll")                                                     \
        for (int r = 0; r < 2; ++r) {                                         \
            int s = r * 256 + tid;                                            \
            int row = s >> 3, gc = (s & 7) ^ (row & 7);                       \
            gld_lds16(kb + (size_t)(m0s + row) * HD_ + gc * 8,                \
                      &Ks[buf][(size_t)s * 8]);                               \
        }                                                                     \
        _Pragma("unroll")                                                     \
        for (int r = 0; r < 2; ++r) {                                         \
            int s = r * 256 + tid;                                            \
            int row = s >> 3, gc = (s & 7) ^ (row & 7);                       \
            gld_lds16(vb + (size_t)row * M_ + m0s + gc * 8,                   \
                      &Vs[buf][(size_t)s * 8]);                               \
        }                                                                     \
    }

    // prologue: stage tile 0, drain, converge
    STAGE_KV(0, 0)
    asm volatile("s_waitcnt vmcnt(0)" ::: "memory");
    __builtin_amdgcn_s_barrier();

    for (int mt = 0; mt < 16; ++mt) {
        const int cur = mt & 1;
        if (mt < 15) STAGE_KV(cur ^ 1, mt + 1)   // prefetch next tile (async)

        const unsigned short* KsC = &Ks[cur][0];
        const unsigned short* VsC = &Vs[cur][0];

        bf16x8 va[3][2];
        #pragma unroll
        for (int ot = 0; ot < 3; ++ot) {
            va[ot][0] = frag_ld(VsC, ot * 16 + ln, quad);
            va[ot][1] = frag_ld(VsC, ot * 16 + ln, 4 + quad);
        }
        bf16x8 ka[4][2];
        #pragma unroll
        for (int t = 0; t < 4; ++t) {
            ka[t][0] = frag_ld(KsC, t * 16 + ln, quad);
            ka[t][1] = (quad < 2) ? frag_ld(KsC, t * 16 + ln, 4 + quad) : zero8;
        }

        #pragma unroll
        for (int t = 0; t < 4; ++t) {
            #pragma unroll
            for (int qt = 0; qt < 4; ++qt) {
                f32x4 s = (f32x4){0.f, 0.f, 0.f, 0.f};
                s = __builtin_amdgcn_mfma_f32_16x16x32_bf16(ka[t][0], qb[qt][0], s, 0, 0, 0);
                s = __builtin_amdgcn_mfma_f32_16x16x32_bf16(ka[t][1], qb[qt][1], s, 0, 0, 0);
                float p0 = fast_exp2(s[0]);
                float p1 = fast_exp2(s[1]);
                float p2 = fast_exp2(s[2]);
                float p3 = fast_exp2(s[3]);
                rs[qt] += (p0 + p1) + (p2 + p3);
                uint2 pk;
                pk.x = (unsigned int)f2bf_trunc(p0) | ((unsigned int)f2bf_trunc(p1) << 16);
                pk.y = (unsigned int)f2bf_trunc(p2) | ((unsigned int)f2bf_trunc(p3) << 16);
                *(uint2*)&Pw[(qt * 16 + ln) * 72 + t * 16 + quad * 4] = pk;
            }
        }

        #pragma unroll
        for (int qt = 0; qt < 4; ++qt) {
            const unsigned short* Pr = &Pw[(qt * 16 + ln) * 72];
            bf16x8 pb0 = *(const bf16x8*)(Pr + quad * 8);
            bf16x8 pb1 = *(const bf16x8*)(Pr + 32 + quad * 8);
            #pragma unroll
            for (int ot = 0; ot < 3; ++ot) {
                O[ot][qt] = __builtin_amdgcn_mfma_f32_16x16x32_bf16(va[ot][0], pb0, O[ot][qt], 0, 0, 0);
                O[ot][qt] = __builtin_amdgcn_mfma_f32_16x16x32_bf16(va[ot][1], pb1, O[ot][qt], 0, 0, 0);
            }
        }

        // end of tile: next tile's staging has had the whole compute phase to
        // land; drain it and converge before overwriting the other buffer.
        asm volatile("s_waitcnt vmcnt(0)" ::: "memory");
        __builtin_amdgcn_sched_barrier(0);
        __builtin_amdgcn_s_barrier();
        __builtin_amdgcn_sched_barrier(0);
    }
#undef STAGE_KV

    float inv[4];
    #pragma unroll
    for (int qt = 0; qt < 4; ++qt) {
        float x = rs[qt];
        x += __shfl_xor(x, 16);
        x += __shfl_xor(x, 32);
        inv[qt] = 1.0f / x;
    }

    const int b = bh >> 3, h = bh & 7;
    #pragma unroll
    for (int ot = 0; ot < 3; ++ot)
        #pragma unroll
        for (int qt = 0; qt < 4; ++qt) {
            size_t grow = (size_t)b * N_ + n0w + qt * 16 + ln;
            int gcol = h * HD_ + ot * 16 + quad * 4;
            *(uint2*)&of[grow * C_ + gcol] =
                pack4_rne(O[ot][qt][0] * inv[qt], O[ot][qt][1] * inv[qt],
                          O[ot][qt][2] * inv[qt], O[ot][qt][3] * inv[qt]);
        }
}

extern "C" void kernel_launch(void* const* d_in, const int* in_sizes, int n_in,
                              void* d_out, int out_size, void* d_ws, size_t ws_size,
                              hipStream_t stream) {
    const float* q_x   = (const float*)d_in[0];
    const float* kv_x  = (const float*)d_in[1];
    const float* Wq    = (const float*)d_in[2];
    const float* Wkv   = (const float*)d_in[3];
    const float* Wproj = (const float*)d_in[4];
    const float* bproj = (const float*)d_in[5];
    float* out = (float*)d_out;

    unsigned short* qbf     = (unsigned short*)d_ws;  // [B,H,N,48] scaled
    unsigned short* kbf     = qbf     + 6291456;      // [B,H,M,48]
    unsigned short* vbf     = kbf     + 1572864;      // [B,H,48,M]
    unsigned short* qres    = vbf     + 1572864;      // [B,N,384] bf16 residual
    unsigned short* of      = qres    + 6291456;      // [B,N,384] bf16 attn out
    unsigned short* qx_bf   = of      + 6291456;      // [B,N,384] bf16
    unsigned short* kvx_bf  = qx_bf   + 6291456;      // [B,M,384] bf16
    unsigned short* Wq_t    = kvx_bf  + 1572864;      // [384][384]
    unsigned short* Wkv_t   = Wq_t    + 147456;       // [768][384]
    unsigned short* Wproj_t = Wkv_t   + 294912;       // [384][384]

    dim3 blk(256);

    // fused activation convert + weight transpose
    prep<<<dim3(7824), blk, 0, stream>>>(q_x, qx_bf, kv_x, kvx_bf,
                                         Wq, Wkv, Wproj, Wq_t, Wkv_t, Wproj_t);

    // fused q-proj + kv-proj (m97-style, global_load_lds staging)
    gemm_qkv<<<dim3(576), blk, 0, stream>>>(
        qx_bf, kvx_bf, Wq_t, Wkv_t, qbf, qres, kbf, vbf);

    // attention: 512 blocks x 256 q-rows, LDS-staged K/V double-buffer
    attn_mfma<<<dim3(32, 16), blk, 0, stream>>>(qbf, kbf, vbf, of);

    // out = qres + of @ Wproj + bproj
    gemm_out<<<dim3(384), blk, 0, stream>>>(of, Wproj_t, out, qres, bproj);
}